// Round 8
// baseline (955.821 us; speedup 1.0000x reference)
//
#include <hip/hip_runtime.h>
#include <hip/hip_bf16.h>

// Sizes (fixed by the problem)
#define B_    64
#define N_    100
#define R_    9900
#define OBJD  5
#define EFF   100

typedef __bf16 bf16x8 __attribute__((ext_vector_type(8)));
typedef __bf16 bf16x2 __attribute__((ext_vector_type(2)));
typedef float  f32x4  __attribute__((ext_vector_type(4)));

// Native f32->bf16 (RNE): compiler emits v_cvt_pk_bf16_f32.
__device__ __forceinline__ ushort f2bf(float f) {
    __bf16 h = (__bf16)f;
    return __builtin_bit_cast(ushort, h);
}
__device__ __forceinline__ unsigned pk2(float a, float b) {
    bf16x2 v; v[0] = (__bf16)a; v[1] = (__bf16)b;
    return __builtin_bit_cast(unsigned, v);
}
__device__ __forceinline__ float bf2f(ushort u) {
    union { unsigned u; float f; } x; x.u = ((unsigned)u) << 16;
    return x.f;
}

// ---------------------------------------------------------------------------
// Prepped weight region WTR (ushort offsets):
//   rel P1 @0      [160c][40k]   W1 LDS image (k<11)       6400
//   rel P2 @6400   [160c][168k]  W2 (legacy, unused)      26880
//   rel P3 @33280  [112c][168k]  W3 (legacy, unused)      18816
//   obj imgs @52096: 8 x [160c][72k] chunk images (oW1 remapped, oW2, oW3)
//   W2F @144256: frag-packed W2 [ct0..9][ks0..4][lane][8]  25600
//   W3F @169856: frag-packed W3 [ct0..6][ks0..4][lane][8]  17920
// Frag packing matches the MFMA B-frag lane map: a wave's 64 lanes read one
// contiguous 1KB line per (ct,ks) -> perfectly coalesced global_load_dwordx4.
// ---------------------------------------------------------------------------
#define WTR_OBJ 52096
#define W2F_OFF 144256
#define W3F_OFF 169856

__global__ __launch_bounds__(256) void k_prepw(
    const float* __restrict__ W1, const float* __restrict__ W2,
    const float* __restrict__ W3, const float* __restrict__ O1,
    const float* __restrict__ O2, const float* __restrict__ O3,
    ushort* __restrict__ WTR)
{
    const int img = blockIdx.x;   // 0..12
    if (img == 0) {
        for (int idx = threadIdx.x; idx < 6400; idx += 256) {
            const int c = idx / 40, k = idx - (idx/40)*40;
            WTR[idx] = f2bf((c < 150 && k < 11) ? W1[k*150 + c] : 0.f);
        }
    } else if (img == 1) {
        for (int idx = threadIdx.x; idx < 26880; idx += 256) {
            const int c = idx / 168, k = idx - (idx/168)*168;
            WTR[6400 + idx] = f2bf((c < 150 && k < 150) ? W2[k*150 + c] : 0.f);
        }
    } else if (img == 2) {
        for (int idx = threadIdx.x; idx < 18816; idx += 256) {
            const int c = idx / 168, k = idx - (idx/168)*168;
            WTR[33280 + idx] = f2bf((c < 100 && k < 150) ? W3[k*100 + c] : 0.f);
        }
    } else if (img == 11) {   // W2F frag-packed
        for (int idx = threadIdx.x; idx < 25600; idx += 256) {
            const int ctks = idx >> 9;              // 0..49
            const int ct = ctks / 5, ks = ctks - ct*5;
            const int lane = (idx >> 3) & 63, e = idx & 7;
            const int c = ct*16 + (lane & 15);
            const int k = ks*32 + (lane >> 4)*8 + e;
            WTR[W2F_OFF + idx] = f2bf((c < 150 && k < 150) ? W2[k*150 + c] : 0.f);
        }
    } else if (img == 12) {   // W3F frag-packed
        for (int idx = threadIdx.x; idx < 17920; idx += 256) {
            const int ctks = idx >> 9;              // 0..34
            const int ct = ctks / 5, ks = ctks - ct*5;
            const int lane = (idx >> 3) & 63, e = idx & 7;
            const int c = ct*16 + (lane & 15);
            const int k = ks*32 + (lane >> 4)*8 + e;
            WTR[W3F_OFF + idx] = f2bf((c < 100 && k < 150) ? W3[k*100 + c] : 0.f);
        }
    } else {
        const int j = img - 3;   // 0..7
        ushort* dst = WTR + WTR_OBJ + (size_t)j*11520;
        for (int idx = threadIdx.x; idx < 11520; idx += 256) {
            const int cc = idx / 72, kk = idx - (idx/72)*72;
            float v = 0.f;
            if (kk < 64) {
                if (j < 4) {            // oW1, remapped input cols
                    const int kg = j*64 + kk;
                    int row = -1;
                    if (kg < 5) row = kg;
                    else if (kg >= 8 && kg < 108) row = kg - 3;      // ER hi
                    else if (kg >= 108 && kg < 208) row = kg - 103;  // ER lo
                    if (cc < 100 && row >= 0) v = O1[row*100 + cc];
                } else if (j < 6) {     // oW2
                    const int kg = (j-4)*64 + kk;
                    if (cc < 100 && kg < 100) v = O2[kg*100 + cc];
                } else {                // oW3
                    const int kg = (j-6)*64 + kk;
                    if (cc < 2 && kg < 100) v = O3[kg*2 + cc];
                }
            }
            dst[idx] = f2bf(v);
        }
    }
}

// ---------------------------------------------------------------------------
// K2: persistent fused gather + relational MLP + FUSED SCATTER.
// Round 8: 128-r TILES — same work, HALF the barriers per r (7 per 128 r vs
// 14).  Each phase runs 2x the MFMAs per barrier so barrier-drain, W-load
// latency and LDS round-trips amortize 2x.  1 block/CU accepted (unified
// VGPR+AGPR file makes 2-block residency unreachable, r5-r7 evidence).
// W1 in LDS; W2/W3 global frag-packed (LDS budget).  512 blocks (b x 8 oct).
// LDS (ushort offsets), staging stride 136 (128 r + 8 pad):
// ---------------------------------------------------------------------------
#define SSTR  136
#define LW1   0       // [160][40]    6400
#define LBA   6400    // [112][136]  15232  SR stage / ebuf; rows 100..111 zero
#define LBB   21632   // [112][136]  15232  RR stage; rows 100..111 zero
#define LACT  36864   // [128][168]  21504
#define LBIAS 58368   // 400 fp32    800
#define LGB   59168   // [128][24]   3072  (gather out; cols 11..23 zero)
#define LTOT  62240   // 124,480 B (<= 163,840)
#define NT128 78      // ceil(9900/128)

__global__ __launch_bounds__(512, 1) void k_relmlp_p(
    const float* __restrict__ obj, const float* __restrict__ SR,
    const float* __restrict__ RR, const float* __restrict__ RI,
    const ushort* __restrict__ WTR,
    const float* __restrict__ b1, const float* __restrict__ b2,
    const float* __restrict__ b3, float* __restrict__ ER)
{
    __shared__ __align__(16) ushort lds[LTOT];
    const int t   = threadIdx.x;
    const int b   = blockIdx.x >> 3;
    const int oct = blockIdx.x & 7;
    const int lane = t & 63, w = t >> 6;
    const int lo = lane & 15, hi = lane >> 4;
    const int mt = w & 3, nh = w >> 2;      // m-tile base, n-half (MLP phases)
    const int q  = t & 7,  rr = t >> 3;     // gather: 8 lanes per row (rr 0..63)

    ushort* bufA = lds + LBA;
    ushort* bufB = lds + LBB;
    ushort* act  = lds + LACT;
    ushort* gb   = lds + LGB;
    const float* bias = (const float*)(lds + LBIAS);

    // ---- block-start: W1 to LDS; biases; zero pads ----
    #pragma unroll
    for (int j = 0; j < 2; ++j) {          // W1: 800 uint4
        const int idx = t + j*512;
        if (idx < 800)
            reinterpret_cast<uint4*>(lds)[idx] =
                reinterpret_cast<const uint4*>(WTR)[idx];
    }
    {
        float* bias_w = (float*)(lds + LBIAS);
        if (t < 150)      bias_w[t] = b1[t];
        else if (t < 300) bias_w[t] = b2[t-150];
        else if (t < 400) bias_w[t] = b3[t-300];
    }
    if (t < 408) {   // rows 100..111 of bufA/bufB = 204 uint4 each
        ushort* base = ((t < 204) ? bufA : bufB) + 100*SSTR;
        const int k = (t < 204) ? t : t - 204;
        *reinterpret_cast<uint4*>(base + k*8) = make_uint4(0u, 0u, 0u, 0u);
    }
    if (t < 128) {   // gbuf static pad cols 11..23
        ushort* gb0 = gb + t*24;
        gb0[11] = 0;
        *reinterpret_cast<ushort4*>(&gb0[12]) = make_ushort4(0,0,0,0);
        *reinterpret_cast<ushort4*>(&gb0[16]) = make_ushort4(0,0,0,0);
        *reinterpret_cast<ushort4*>(&gb0[20]) = make_ushort4(0,0,0,0);
    }

    // ---- obj slice to registers: q-lane covers n = q*13 .. q*13+12 ----
    float objv[13][5];
    {
        const int n0 = q*13;
        #pragma unroll
        for (int i = 0; i < 13; ++i) {
            const int n = n0 + i;
            #pragma unroll
            for (int d = 0; d < 5; ++d)
                objv[i][d] = (n < N_) ? obj[(size_t)b*500 + n*5 + d] : 0.f;
        }
    }

    const int tile0 = (oct*NT128) >> 3;
    const int tile1 = ((oct+1)*NT128) >> 3;

    f32x4 acc_er[7];
    #pragma unroll
    for (int ct = 0; ct < 7; ++ct) acc_er[ct] = (f32x4){0.f, 0.f, 0.f, 0.f};

    // ---- staging: 100n x 128r fp32 -> bf16 LDS [n][r] (3200 float4) ----
    float4 psr[7], prr[7];
    float pri = 0.f, pri_n = 0.f;
    auto load4 = [&](float4* p, const float* M, int tile) {
        const int rr0 = tile*128;
        const int nr = (R_ - rr0 < 128) ? R_ - rr0 : 128;
        #pragma unroll
        for (int i = 0; i < 7; ++i) {
            const int idx = t + i*512;
            const int ci = idx < 3200 ? idx : 3199;
            const int n = ci >> 5, qq = ci & 31;
            const int col = (qq*4 < nr) ? qq*4 : 0;
            p[i] = *reinterpret_cast<const float4*>(
                &M[((size_t)b*N_ + n)*R_ + rr0 + col]);
        }
    };
    auto store4 = [&](const float4* p, ushort* dst, int nrow) {
        #pragma unroll
        for (int i = 0; i < 7; ++i) {
            const int idx = t + i*512;
            if (idx < 3200) {
                const int n = idx >> 5, qq = idx & 31;
                float4 v = p[i];
                if (qq*4 >= nrow) v = make_float4(0.f, 0.f, 0.f, 0.f);
                uint2 u; u.x = pk2(v.x, v.y); u.y = pk2(v.z, v.w);
                *reinterpret_cast<uint2*>(&dst[n*SSTR + qq*4]) = u;
            }
        }
    };
    auto loadRI = [&](int tile) -> float {
        const int rr0 = tile*128;
        return (t < 128 && rr0 + t < R_) ? RI[(size_t)b*R_ + rr0 + t] : 0.f;
    };

    load4(psr, SR, tile0);
    load4(prr, RR, tile0);
    pri = loadRI(tile0);
    __syncthreads();                       // resident LDS + pads ready

    for (int tile = tile0; tile < tile1; ++tile) {
        const int r0 = tile*128;
        const int nrow = (R_ - r0 < 128) ? R_ - r0 : 128;

        // ---- stage SR->bufA, RR->bufB; prefetch next tile ----
        store4(psr, bufA, nrow);
        store4(prr, bufB, nrow);
        if (tile + 1 < tile1) {
            load4(psr, SR, tile+1);
            load4(prr, RR, tile+1);
            pri_n = loadRI(tile+1);
        }
        __syncthreads();                   // B1: staged

        // ---- gather: 8 lanes/row, obj in VGPR, two 64-row halves ----
        {
            #pragma unroll
            for (int h = 0; h < 2; ++h) {
                float s0=0.f,s1=0.f,s2=0.f,s3=0.f,s4=0.f;
                float g0=0.f,g1=0.f,g2=0.f,g3=0.f,g4=0.f;
                const int n0 = q*13;
                const int rcol = h*64 + rr;
                #pragma unroll
                for (int i = 0; i < 13; ++i) {
                    const int n = n0 + i;   // n>=100 rows zeroed pad -> safe
                    const float ms = bf2f(bufA[n*SSTR + rcol]);
                    const float mr = bf2f(bufB[n*SSTR + rcol]);
                    s0 += ms*objv[i][0]; s1 += ms*objv[i][1]; s2 += ms*objv[i][2];
                    s3 += ms*objv[i][3]; s4 += ms*objv[i][4];
                    g0 += mr*objv[i][0]; g1 += mr*objv[i][1]; g2 += mr*objv[i][2];
                    g3 += mr*objv[i][3]; g4 += mr*objv[i][4];
                }
                #pragma unroll
                for (int msk = 1; msk < 8; msk <<= 1) {
                    s0 += __shfl_xor(s0, msk); s1 += __shfl_xor(s1, msk);
                    s2 += __shfl_xor(s2, msk); s3 += __shfl_xor(s3, msk);
                    s4 += __shfl_xor(s4, msk);
                    g0 += __shfl_xor(g0, msk); g1 += __shfl_xor(g1, msk);
                    g2 += __shfl_xor(g2, msk); g3 += __shfl_xor(g3, msk);
                    g4 += __shfl_xor(g4, msk);
                }
                if (q < 5) {
                    const float sv = (q==0)?s0:(q==1)?s1:(q==2)?s2:(q==3)?s3:s4;
                    const float gv = (q==0)?g0:(q==1)?g1:(q==2)?g2:(q==3)?g3:g4;
                    gb[rcol*24 + q]     = f2bf(sv);
                    gb[rcol*24 + 5 + q] = f2bf(gv);
                }
            }
            if (t < 128) gb[t*24 + 10] = f2bf(pri);   // RI col
            pri = pri_n;
        }
        __syncthreads();                   // B2: gb ready; bufA free for ebuf

        // ---- L1: 11(32) -> 150   (gb -> act; W1 from LDS; 2 m-halves) ----
        {
            #pragma unroll
            for (int mh = 0; mh < 2; ++mh) {
                const int mt8 = mh*4 + mt;
                f32x4 acc[5];
                #pragma unroll
                for (int j = 0; j < 5; ++j) {
                    const int c = (nh*5 + j)*16 + lo;
                    const float bv = (c < 150) ? bias[c] : 0.f;
                    acc[j][0]=bv; acc[j][1]=bv; acc[j][2]=bv; acc[j][3]=bv;
                }
                bf16x8 a = {};
                if (hi < 2)     // k 16..31 zero
                    a = *reinterpret_cast<const bf16x8*>(
                        &gb[(mt8*16 + lo)*24 + hi*8]);
                #pragma unroll
                for (int j = 0; j < 5; ++j) {
                    const int ct = nh*5 + j;
                    const bf16x8 bb = *reinterpret_cast<const bf16x8*>(
                        &lds[LW1 + (ct*16 + lo)*40 + hi*8]);
                    acc[j] = __builtin_amdgcn_mfma_f32_16x16x32_bf16(a, bb, acc[j], 0,0,0);
                }
                #pragma unroll
                for (int j = 0; j < 5; ++j) {
                    const int ct = nh*5 + j;
                    #pragma unroll
                    for (int r = 0; r < 4; ++r)
                        act[(mt8*16 + hi*4 + r)*168 + ct*16 + lo] =
                            f2bf(fmaxf(acc[j][r], 0.f));
                }
            }
            __syncthreads();               // B3: act(L1) ready
        }
        // ---- L2: 150(160) -> 150  (act x W2F-global, 2 m-halves, 50 MFMA) ----
        {
            const ushort* w2p = WTR + W2F_OFF + (size_t)lane*8 + (size_t)nh*12800;
            asm volatile("" : "+v"(w2p));  // fresh base per tile: no hoist/CSE
            f32x4 acc2[2][5];
            #pragma unroll
            for (int mh = 0; mh < 2; ++mh)
                #pragma unroll
                for (int j = 0; j < 5; ++j) {
                    const int c = (nh*5 + j)*16 + lo;
                    const float bv = (c < 150) ? bias[150 + c] : 0.f;
                    acc2[mh][j][0]=bv; acc2[mh][j][1]=bv;
                    acc2[mh][j][2]=bv; acc2[mh][j][3]=bv;
                }
            #pragma unroll
            for (int mh = 0; mh < 2; ++mh) {
                const int mt8 = mh*4 + mt;
                #pragma unroll
                for (int ks = 0; ks < 5; ++ks) {
                    const bf16x8 a = *reinterpret_cast<const bf16x8*>(
                        &act[(mt8*16 + lo)*168 + ks*32 + hi*8]);
                    #pragma unroll
                    for (int j = 0; j < 5; ++j) {
                        const bf16x8 bb = *reinterpret_cast<const bf16x8*>(
                            w2p + ((j*5 + ks) << 9));
                        acc2[mh][j] = __builtin_amdgcn_mfma_f32_16x16x32_bf16(
                            a, bb, acc2[mh][j], 0,0,0);
                    }
                }
            }
            __syncthreads();               // B4: all act(L1) reads done
            #pragma unroll
            for (int mh = 0; mh < 2; ++mh) {
                const int mt8 = mh*4 + mt;
                #pragma unroll
                for (int j = 0; j < 5; ++j) {
                    const int ct = nh*5 + j;
                    #pragma unroll
                    for (int r = 0; r < 4; ++r)
                        act[(mt8*16 + hi*4 + r)*168 + ct*16 + lo] =
                            f2bf(fmaxf(acc2[mh][j][r], 0.f));
                }
            }
            __syncthreads();               // B5: act(L2) ready
        }
        // ---- L3: 150(160) -> 100  (act x W3F-global -> ebuf=bufA) ----
        {
            const ushort* w3p = WTR + W3F_OFF + (size_t)lane*8 + (size_t)nh*10240;
            asm volatile("" : "+v"(w3p));
            const int nct = nh ? 3 : 4;
            #pragma unroll
            for (int mh = 0; mh < 2; ++mh) {
                const int mt8 = mh*4 + mt;
                f32x4 acc[4];
                #pragma unroll
                for (int j = 0; j < 4; ++j) {
                    const int c = (nh*4 + j)*16 + lo;
                    const float bv = (c < 100) ? bias[300 + c] : 0.f;
                    acc[j][0]=bv; acc[j][1]=bv; acc[j][2]=bv; acc[j][3]=bv;
                }
                #pragma unroll
                for (int ks = 0; ks < 5; ++ks) {
                    const bf16x8 a = *reinterpret_cast<const bf16x8*>(
                        &act[(mt8*16 + lo)*168 + ks*32 + hi*8]);
                    #pragma unroll
                    for (int j = 0; j < 4; ++j) {
                        if (j < nct) {
                            const bf16x8 bb = *reinterpret_cast<const bf16x8*>(
                                w3p + ((j*5 + ks) << 9));
                            acc[j] = __builtin_amdgcn_mfma_f32_16x16x32_bf16(a, bb, acc[j], 0,0,0);
                        }
                    }
                }
                // bufA consumed by gather (B2 passed) -> safe to write ebuf
                #pragma unroll
                for (int j = 0; j < 4; ++j) {
                    if (j < nct) {
                        const int e = (nh*4 + j)*16 + lo;
                        if (e < 100) {
                            uint2 u;
                            u.x = pk2(fmaxf(acc[j][0], 0.f), fmaxf(acc[j][1], 0.f));
                            u.y = pk2(fmaxf(acc[j][2], 0.f), fmaxf(acc[j][3], 0.f));
                            *reinterpret_cast<uint2*>(
                                &bufA[e*SSTR + mt8*16 + hi*4]) = u;
                        }
                    }
                }
            }
            __syncthreads();   // B6: ebuf complete before scatter reads
        }

        // ---- fused scatter: acc_er += RR_tile x E_tile  (K=128, 28 MFMA) ----
        if (w < 7) {
            #pragma unroll
            for (int ks = 0; ks < 4; ++ks) {
                const bf16x8 a = *reinterpret_cast<const bf16x8*>(
                    &bufB[(w*16 + lo)*SSTR + ks*32 + hi*8]);
                #pragma unroll
                for (int ct = 0; ct < 7; ++ct) {
                    const bf16x8 bb = *reinterpret_cast<const bf16x8*>(
                        &bufA[(ct*16 + lo)*SSTR + ks*32 + hi*8]);
                    acc_er[ct] = __builtin_amdgcn_mfma_f32_16x16x32_bf16(
                        a, bb, acc_er[ct], 0, 0, 0);
                }
            }
        }
        __syncthreads();   // B7: scatter reads done before next tile's staging
    }

    // ---- ER partials: plain stores to this block's oct-slab ----
    if (w < 7) {
        float* ERq = ER + ((size_t)oct*B_ + b)*(size_t)(N_*EFF);
        #pragma unroll
        for (int ct = 0; ct < 7; ++ct) {
            const int e = ct*16 + lo;
            if (e < EFF) {
                #pragma unroll
                for (int rg = 0; rg < 4; ++rg) {
                    const int n = w*16 + hi*4 + rg;
                    if (n < N_)
                        ERq[n*EFF + e] = acc_er[ct][rg];
                }
            }
        }
    }
}

// ---------------------------------------------------------------------------
// Weight-image register staging (validated).
// ---------------------------------------------------------------------------
__device__ __forceinline__ void img_load(const ushort* __restrict__ g,
                                         uint4* pre, int t) {
    #pragma unroll
    for (int j = 0; j < 6; ++j) {
        int idx = t + j*256;
        int cidx = idx < 1440 ? idx : 1439;
        pre[j] = *reinterpret_cast<const uint4*>(g + (size_t)cidx*8);
    }
}
__device__ __forceinline__ void img_store(const uint4* pre, ushort* wt, int t) {
    #pragma unroll
    for (int j = 0; j < 6; ++j) {
        int idx = t + j*256;
        if (idx < 1440)
            *reinterpret_cast<uint4*>(wt + (size_t)idx*8) = pre[j];
    }
}

// ---------------------------------------------------------------------------
// MFMA dense layer for objmlp (validated round 6).
// ---------------------------------------------------------------------------
template<int COUT, int NCHUNK, int LASTKS, int NCT, bool RELU, int EPI, int ASTR>
__device__ __forceinline__ void mfma_layerO(
    const ushort* __restrict__ WT, const float* __restrict__ Bias,
    ushort* act, ushort* wt, int t, float* gout, int grow0)
{
    const int lane = t & 63;
    const int wv   = t >> 6;
    const int lo   = lane & 15;
    const int hi   = lane >> 4;

    f32x4 acc[2][NCT];
    #pragma unroll
    for (int ct = 0; ct < NCT; ++ct) {
        const int c = ct*16 + lo;
        const float bv = (c < COUT) ? Bias[c] : 0.f;
        #pragma unroll
        for (int m = 0; m < 2; ++m) {
            acc[m][ct][0] = bv; acc[m][ct][1] = bv;
            acc[m][ct][2] = bv; acc[m][ct][3] = bv;
        }
    }

    uint4 pre[6];
    img_load(WT, pre, t);
    #pragma unroll
    for (int q = 0; q < NCHUNK; ++q) {
        __syncthreads();
        img_store(pre, wt, t);
        if (q + 1 < NCHUNK) img_load(WT + (size_t)(q+1)*11520, pre, t);
        __syncthreads();
        const int nks = (q == NCHUNK-1) ? LASTKS : 2;
        #pragma unroll
        for (int ks = 0; ks < 2; ++ks) {
            if (ks < nks) {
                const int kg = q*64 + ks*32;
                const bf16x8 a0 = *reinterpret_cast<const bf16x8*>(
                    &act[(wv*32 +      lo)*ASTR + kg + hi*8]);
                const bf16x8 a1 = *reinterpret_cast<const bf16x8*>(
                    &act[(wv*32 + 16 + lo)*ASTR + kg + hi*8]);
                #pragma unroll
                for (int ct = 0; ct < NCT; ++ct) {
                    const bf16x8 b = *reinterpret_cast<const bf16x8*>(
                        &wt[(ct*16 + lo)*72 + ks*32 + hi*8]);
                    acc[0][ct] = __builtin_amdgcn_mfma_f32_16x16x32_bf16(
                        a0, b, acc[0][ct], 0, 0, 0);
                    acc[1][ct] = __builtin_amdgcn_mfma_f32_16x16x32_bf16(
                        a1, b, acc[1][ct], 0, 0, 0);
                }
            }
        }
    }

    __syncthreads();
    if (EPI == 0) {
        #pragma unroll
        for (int m = 0; m < 2; ++m)
            #pragma unroll
            for (int ct = 0; ct < NCT; ++ct)
                #pragma unroll
                for (int r = 0; r < 4; ++r) {
                    float v = acc[m][ct][r];
                    if (RELU) v = fmaxf(v, 0.f);
                    act[(wv*32 + m*16 + hi*4 + r)*ASTR + ct*16 + lo] = f2bf(v);
                }
    } else {
        #pragma unroll
        for (int m = 0; m < 2; ++m)
            #pragma unroll
            for (int r = 0; r < 4; ++r)
                if (lo < 2)
                    gout[(size_t)(grow0 + wv*32 + m*16 + hi*4 + r)*2 + lo] =
                        acc[m][0][r];
    }
    __syncthreads();
}

// ---------------------------------------------------------------------------
// K4: object MLP via MFMA (validated round 6). 50 blocks x 128 rows.
// ER is 8 per-oct slabs; sum them during the load.
// ---------------------------------------------------------------------------
#define OSTR 232
#define ERSL ((size_t)B_*N_*EFF)

__global__ __launch_bounds__(256, 1) void k_objmlp_mfma(
    const float* __restrict__ obj, const float* __restrict__ ER,
    const ushort* __restrict__ WO,
    const float* __restrict__ ob1, const float* __restrict__ ob2,
    const float* __restrict__ ob3, float* __restrict__ out)
{
    __shared__ __align__(16) ushort act[128*OSTR];
    __shared__ __align__(16) ushort wt[160*72];
    const int t = threadIdx.x;
    const int rowbase = blockIdx.x * 128;

    float4 per[13];
    #pragma unroll
    for (int j = 0; j < 13; ++j) {
        const int idx = t + j*256;
        const int ci = idx < 3200 ? idx : 3199;
        const int row = ci / 25, c = ci - row*25;
        const float* p = &ER[(size_t)(rowbase + row)*100 + c*4];
        float4 s = make_float4(0.f, 0.f, 0.f, 0.f);
        #pragma unroll
        for (int sl = 0; sl < 8; ++sl) {
            const float4 a = *reinterpret_cast<const float4*>(p + (size_t)sl*ERSL);
            s.x += a.x; s.y += a.y; s.z += a.z; s.w += a.w;
        }
        per[j] = s;
    }
    #pragma unroll
    for (int j = 0; j < 13; ++j) {
        const int idx = t + j*256;
        if (idx < 3200) {
            const int row = idx / 25, c = idx - row*25;
            ushort h[4], l[4];
            #pragma unroll
            for (int k = 0; k < 4; ++k) {
                const float f = ((const float*)&per[j])[k];
                h[k] = f2bf(f);
                l[k] = f2bf(f - bf2f(h[k]));
            }
            *reinterpret_cast<ushort4*>(&act[row*OSTR + 8 + c*4]) =
                make_ushort4(h[0], h[1], h[2], h[3]);
            *reinterpret_cast<ushort4*>(&act[row*OSTR + 108 + c*4]) =
                make_ushort4(l[0], l[1], l[2], l[3]);
        }
    }
    #pragma unroll
    for (int j = 0; j < 3; ++j) {
        const int idx = t + j*256;
        if (idx < 640) {
            const int row = idx / 5, d = idx - row*5;
            act[row*OSTR + d] = f2bf(obj[(size_t)(rowbase + row)*5 + d]);
        }
    }
    #pragma unroll
    for (int j = 0; j < 2; ++j) {
        const int idx = t + j*256;
        if (idx < 384) {
            const int row = idx / 3, c = 5 + (idx - row*3);
            act[row*OSTR + c] = 0;
        }
    }
    #pragma unroll
    for (int j = 0; j < 2; ++j) {
        const int idx = t + j*256;
        if (idx < 512) {
            const int row = idx >> 2, p = idx & 3;
            *reinterpret_cast<ushort4*>(&act[row*OSTR + 208 + p*4]) =
                make_ushort4(0, 0, 0, 0);
        }
    }

    mfma_layerO<100, 4, 1, 7, true,  0, OSTR>(WO,           ob1, act, wt, t, nullptr, 0);
    mfma_layerO<100, 2, 2, 7, true,  0, OSTR>(WO + 4*11520, ob2, act, wt, t, nullptr, 0);
    mfma_layerO<2,   2, 2, 1, false, 2, OSTR>(WO + 6*11520, ob3, act, wt, t, out, rowbase);
}

// ---------------------------------------------------------------------------
extern "C" void kernel_launch(void* const* d_in, const int* in_sizes, int n_in,
                              void* d_out, int out_size, void* d_ws, size_t ws_size,
                              hipStream_t stream)
{
    const float* objects = (const float*)d_in[0];
    const float* SR      = (const float*)d_in[1];
    const float* RR      = (const float*)d_in[2];
    const float* RI      = (const float*)d_in[3];
    const float* rW1 = (const float*)d_in[4];  const float* rb1 = (const float*)d_in[5];
    const float* rW2 = (const float*)d_in[6];  const float* rb2 = (const float*)d_in[7];
    const float* rW3 = (const float*)d_in[8];  const float* rb3 = (const float*)d_in[9];
    const float* oW1 = (const float*)d_in[10]; const float* ob1 = (const float*)d_in[11];
    const float* oW2 = (const float*)d_in[12]; const float* ob2 = (const float*)d_in[13];
    const float* oW3 = (const float*)d_in[14]; const float* ob3 = (const float*)d_in[15];
    float* out = (float*)d_out;

    // Workspace layout (~20.9 MB):
    //   ERp  fp32 [8 oct][B*N][100] = 20,480,000 B  @0   (fully written)
    //   WTR  bf16 187,776 ushorts   =    375,552 B  @20,480,000
    char* ws = (char*)d_ws;
    float*  ERp = (float*)ws;
    ushort* WTR = (ushort*)(ws + (size_t)8*B_*N_*EFF*sizeof(float));

    k_prepw<<<dim3(13), 256, 0, stream>>>(rW1, rW2, rW3, oW1, oW2, oW3, WTR);

    k_relmlp_p<<<dim3(512), 512, 0, stream>>>(objects, SR, RR, RI, WTR,
                                              rb1, rb2, rb3, ERp);

    k_objmlp_mfma<<<dim3(50), 256, 0, stream>>>(objects, ERp, WTR + WTR_OBJ,
                                                ob1, ob2, ob3, out);
}

// Round 9
// 440.988 us; speedup vs baseline: 2.1675x; 2.1675x over previous
//
#include <hip/hip_runtime.h>
#include <hip/hip_bf16.h>

// Sizes (fixed by the problem)
#define B_    64
#define N_    100
#define R_    9900
#define OBJD  5
#define EFF   100

typedef __bf16 bf16x8 __attribute__((ext_vector_type(8)));
typedef __bf16 bf16x2 __attribute__((ext_vector_type(2)));
typedef float  f32x4  __attribute__((ext_vector_type(4)));

// Native f32->bf16 (RNE): compiler emits v_cvt_pk_bf16_f32.
__device__ __forceinline__ ushort f2bf(float f) {
    __bf16 h = (__bf16)f;
    return __builtin_bit_cast(ushort, h);
}
__device__ __forceinline__ unsigned pk2(float a, float b) {
    bf16x2 v; v[0] = (__bf16)a; v[1] = (__bf16)b;
    return __builtin_bit_cast(unsigned, v);
}
__device__ __forceinline__ float bf2f(ushort u) {
    union { unsigned u; float f; } x; x.u = ((unsigned)u) << 16;
    return x.f;
}

// ---------------------------------------------------------------------------
// Prepped weight region WTR (ushort offsets):
//   rel P1 @0      [160c][40k]   W1 LDS image (k<11)       6400
//   rel P2 @6400   [160c][168k]  W2 (legacy, unused)      26880
//   rel P3 @33280  [112c][168k]  W3 (legacy, unused)      18816
//   obj imgs @52096: 8 x [160c][72k] chunk images (oW1 remapped, oW2, oW3)
//   W2F @144256: frag-packed W2 [ct0..9][ks0..4][lane][8]  25600
//   W3F @169856: frag-packed W3 [ct0..6][ks0..4][lane][8]  17920
// ---------------------------------------------------------------------------
#define WTR_OBJ 52096
#define W2F_OFF 144256
#define W3F_OFF 169856

__global__ __launch_bounds__(256) void k_prepw(
    const float* __restrict__ W1, const float* __restrict__ W2,
    const float* __restrict__ W3, const float* __restrict__ O1,
    const float* __restrict__ O2, const float* __restrict__ O3,
    ushort* __restrict__ WTR)
{
    const int img = blockIdx.x;   // 0..12
    if (img == 0) {
        for (int idx = threadIdx.x; idx < 6400; idx += 256) {
            const int c = idx / 40, k = idx - (idx/40)*40;
            WTR[idx] = f2bf((c < 150 && k < 11) ? W1[k*150 + c] : 0.f);
        }
    } else if (img == 1) {
        for (int idx = threadIdx.x; idx < 26880; idx += 256) {
            const int c = idx / 168, k = idx - (idx/168)*168;
            WTR[6400 + idx] = f2bf((c < 150 && k < 150) ? W2[k*150 + c] : 0.f);
        }
    } else if (img == 2) {
        for (int idx = threadIdx.x; idx < 18816; idx += 256) {
            const int c = idx / 168, k = idx - (idx/168)*168;
            WTR[33280 + idx] = f2bf((c < 100 && k < 150) ? W3[k*100 + c] : 0.f);
        }
    } else if (img == 11) {   // W2F frag-packed
        for (int idx = threadIdx.x; idx < 25600; idx += 256) {
            const int ctks = idx >> 9;              // 0..49
            const int ct = ctks / 5, ks = ctks - ct*5;
            const int lane = (idx >> 3) & 63, e = idx & 7;
            const int c = ct*16 + (lane & 15);
            const int k = ks*32 + (lane >> 4)*8 + e;
            WTR[W2F_OFF + idx] = f2bf((c < 150 && k < 150) ? W2[k*150 + c] : 0.f);
        }
    } else if (img == 12) {   // W3F frag-packed
        for (int idx = threadIdx.x; idx < 17920; idx += 256) {
            const int ctks = idx >> 9;              // 0..34
            const int ct = ctks / 5, ks = ctks - ct*5;
            const int lane = (idx >> 3) & 63, e = idx & 7;
            const int c = ct*16 + (lane & 15);
            const int k = ks*32 + (lane >> 4)*8 + e;
            WTR[W3F_OFF + idx] = f2bf((c < 100 && k < 150) ? W3[k*100 + c] : 0.f);
        }
    } else {
        const int j = img - 3;   // 0..7
        ushort* dst = WTR + WTR_OBJ + (size_t)j*11520;
        for (int idx = threadIdx.x; idx < 11520; idx += 256) {
            const int cc = idx / 72, kk = idx - (idx/72)*72;
            float v = 0.f;
            if (kk < 64) {
                if (j < 4) {            // oW1, remapped input cols
                    const int kg = j*64 + kk;
                    int row = -1;
                    if (kg < 5) row = kg;
                    else if (kg >= 8 && kg < 108) row = kg - 3;      // ER hi
                    else if (kg >= 108 && kg < 208) row = kg - 103;  // ER lo
                    if (cc < 100 && row >= 0) v = O1[row*100 + cc];
                } else if (j < 6) {     // oW2
                    const int kg = (j-4)*64 + kk;
                    if (cc < 100 && kg < 100) v = O2[kg*100 + cc];
                } else {                // oW3
                    const int kg = (j-6)*64 + kk;
                    if (cc < 2 && kg < 100) v = O3[kg*2 + cc];
                }
            }
            dst[idx] = f2bf(v);
        }
    }
}

// ---------------------------------------------------------------------------
// K2 round 9: PRODUCER-CONSUMER WAVE SPECIALIZATION.
// Waves 0-3 (M): per 64-r tile each wave owns 16 r-rows end-to-end:
//   gather -> L1 -> L2 -> L3 -> ebuf, using WAVE-PRIVATE act/gb LDS slices
//   (same-wave lgkmcnt ordering, NO barriers inside the MLP).
// Waves 4-7 (S): scatter(k-1) from prev buffers, then stage(k+1) into the
//   alternate buffers (staging latency hides under M's compute; no prefetch
//   registers needed).  acc_er lives ONLY in S-waves; objv ONLY in M-waves;
//   the two loops are disjoint branches -> register sets don't coexist.
// ONE __syncthreads per tile (vs 7).  Barrier counts match across roles.
// LDS (ushort offsets):
// ---------------------------------------------------------------------------
#define LW1   0       // [160][40]  6400
#define LSR0  6400    // SR buf0 [112][72] 8064 (rows 100..111 zero)
#define LSR1  14464   // SR buf1
#define LRR0  22528   // RR buf0
#define LRR1  30592   // RR buf1
#define LEB0  38656   // ebuf0 [112][72] (rows 100..111 zero)
#define LEB1  46720   // ebuf1
#define LACT1 54784   // 4 x [16][168] = 10752 (L1 out, wave-private)
#define LACT2 65536   // 4 x [16][168] = 10752 (L2 out, wave-private)
#define LGB   76288   // 4 x [16][24]  = 1536  (gather out; cols 11..23 zero)
#define LBIAS 77824   // 400 fp32 = 800
#define LTOT  78624   // 157,248 B (<= 163,840)

__global__ __launch_bounds__(512, 1) void k_relmlp_p(
    const float* __restrict__ obj, const float* __restrict__ SR,
    const float* __restrict__ RR, const float* __restrict__ RI,
    const ushort* __restrict__ WTR,
    const float* __restrict__ b1, const float* __restrict__ b2,
    const float* __restrict__ b3, float* __restrict__ ER)
{
    __shared__ __align__(16) ushort lds[LTOT];
    const int t   = threadIdx.x;
    const int b   = blockIdx.x >> 3;
    const int oct = blockIdx.x & 7;
    const int lane = t & 63, w = t >> 6;
    const int lo = lane & 15, hi = lane >> 4;

    const float* bias = (const float*)(lds + LBIAS);
    const int tile0 = (oct*155) >> 3;
    const int tile1 = ((oct+1)*155) >> 3;

    // ---- block-start init (all 512 threads) ----
    #pragma unroll
    for (int j = 0; j < 2; ++j) {          // W1: 800 uint4
        const int idx = t + j*512;
        if (idx < 800)
            reinterpret_cast<uint4*>(lds)[idx] =
                reinterpret_cast<const uint4*>(WTR)[idx];
    }
    {
        float* bias_w = (float*)(lds + LBIAS);
        if (t < 150)      bias_w[t] = b1[t];
        else if (t < 300) bias_w[t] = b2[t-150];
        else if (t < 400) bias_w[t] = b3[t-300];
    }
    #pragma unroll
    for (int j = 0; j < 2; ++j) {          // rows 100..111 of 6 bufs: 648 uint4
        const int idx = t + j*512;
        if (idx < 648) {
            const int bsel = idx / 108, kk = idx - bsel*108;
            *reinterpret_cast<uint4*>(lds + LSR0 + bsel*8064 + 100*72 + kk*8) =
                make_uint4(0u, 0u, 0u, 0u);
        }
    }
    if (t < 64) {    // gb pads cols 11..23 (4 waves x 16 rows)
        ushort* gb0 = lds + LGB + (t >> 4)*384 + (t & 15)*24;
        gb0[11] = 0;
        *reinterpret_cast<ushort4*>(&gb0[12]) = make_ushort4(0,0,0,0);
        *reinterpret_cast<ushort4*>(&gb0[16]) = make_ushort4(0,0,0,0);
        *reinterpret_cast<ushort4*>(&gb0[20]) = make_ushort4(0,0,0,0);
    }

    // ---- staging (S-waves, 256 threads tS in [0,256)) ----
    const int tS = t - 256;
    auto stage = [&](int tile, int pp) {
        const int rr0 = tile*64;
        const int nr = (R_ - rr0 < 64) ? R_ - rr0 : 64;
        ushort* dS = lds + (pp ? LSR1 : LSR0);
        ushort* dR = lds + (pp ? LRR1 : LRR0);
        #pragma unroll
        for (int i = 0; i < 7; ++i) {
            const int idx = tS + i*256;
            if (idx < 1600) {
                const int n = idx >> 4, qq = idx & 15;
                const int col = (qq*4 < nr) ? qq*4 : 0;
                float4 v = *reinterpret_cast<const float4*>(
                    &SR[((size_t)b*N_ + n)*R_ + rr0 + col]);
                if (qq*4 >= nr) v = make_float4(0.f, 0.f, 0.f, 0.f);
                uint2 u; u.x = pk2(v.x, v.y); u.y = pk2(v.z, v.w);
                *reinterpret_cast<uint2*>(&dS[n*72 + qq*4]) = u;
                float4 v2 = *reinterpret_cast<const float4*>(
                    &RR[((size_t)b*N_ + n)*R_ + rr0 + col]);
                if (qq*4 >= nr) v2 = make_float4(0.f, 0.f, 0.f, 0.f);
                uint2 u2; u2.x = pk2(v2.x, v2.y); u2.y = pk2(v2.z, v2.w);
                *reinterpret_cast<uint2*>(&dR[n*72 + qq*4]) = u2;
            }
        }
    };

    if (w >= 4) stage(tile0, tile0 & 1);
    __syncthreads();                       // B0: init + tile0 staged

    if (w < 4) {
        // ================= M-waves: private gather + MLP =================
        const int m = w;
        ushort* act1m = lds + LACT1 + m*2688;
        ushort* act2m = lds + LACT2 + m*2688;
        ushort* gbm   = lds + LGB   + m*384;
        const int q = lane & 7, rl = lane >> 3;

        float objv[13][5];
        {
            const int n0 = q*13;
            #pragma unroll
            for (int i = 0; i < 13; ++i) {
                const int n = n0 + i;
                #pragma unroll
                for (int d = 0; d < 5; ++d)
                    objv[i][d] = (n < N_) ? obj[(size_t)b*500 + n*5 + d] : 0.f;
            }
        }

        for (int k = tile0; k < tile1; ++k) {
            const int p = k & 1;
            const int r0 = k*64;
            ushort* bufS = lds + (p ? LSR1 : LSR0);
            ushort* bufR = lds + (p ? LRR1 : LRR0);
            ushort* eb   = lds + (p ? LEB1 : LEB0);

            // ---- gather: wave-private rows m*16..m*16+15, 2 passes ----
            #pragma unroll
            for (int h = 0; h < 2; ++h) {
                const int lr = h*8 + rl;        // local row 0..15
                const int rT = m*16 + lr;       // tile row 0..63
                float s0=0.f,s1=0.f,s2=0.f,s3=0.f,s4=0.f;
                float g0=0.f,g1=0.f,g2=0.f,g3=0.f,g4=0.f;
                const int n0 = q*13;
                #pragma unroll
                for (int i = 0; i < 13; ++i) {
                    const int n = n0 + i;       // rows 100..103 zeroed pad
                    const float ms = bf2f(bufS[n*72 + rT]);
                    const float mr = bf2f(bufR[n*72 + rT]);
                    s0 += ms*objv[i][0]; s1 += ms*objv[i][1]; s2 += ms*objv[i][2];
                    s3 += ms*objv[i][3]; s4 += ms*objv[i][4];
                    g0 += mr*objv[i][0]; g1 += mr*objv[i][1]; g2 += mr*objv[i][2];
                    g3 += mr*objv[i][3]; g4 += mr*objv[i][4];
                }
                #pragma unroll
                for (int msk = 1; msk < 8; msk <<= 1) {
                    s0 += __shfl_xor(s0, msk); s1 += __shfl_xor(s1, msk);
                    s2 += __shfl_xor(s2, msk); s3 += __shfl_xor(s3, msk);
                    s4 += __shfl_xor(s4, msk);
                    g0 += __shfl_xor(g0, msk); g1 += __shfl_xor(g1, msk);
                    g2 += __shfl_xor(g2, msk); g3 += __shfl_xor(g3, msk);
                    g4 += __shfl_xor(g4, msk);
                }
                if (q < 5) {
                    const float sv = (q==0)?s0:(q==1)?s1:(q==2)?s2:(q==3)?s3:s4;
                    const float gv = (q==0)?g0:(q==1)?g1:(q==2)?g2:(q==3)?g3:g4;
                    gbm[lr*24 + q]     = f2bf(sv);
                    gbm[lr*24 + 5 + q] = f2bf(gv);
                } else if (q == 5) {
                    const int rg = r0 + rT;
                    gbm[lr*24 + 10] =
                        f2bf((rg < R_) ? RI[(size_t)b*R_ + rg] : 0.f);
                }
            }

            // ---- L1: gb[16][32] x W1 -> act1 (private, no barrier) ----
            {
                bf16x8 a = {};
                if (hi < 2)
                    a = *reinterpret_cast<const bf16x8*>(&gbm[lo*24 + hi*8]);
                #pragma unroll
                for (int half = 0; half < 2; ++half) {
                    f32x4 acc[5];
                    #pragma unroll
                    for (int j = 0; j < 5; ++j) {
                        const int c = (half*5 + j)*16 + lo;
                        const float bv = (c < 150) ? bias[c] : 0.f;
                        acc[j][0]=bv; acc[j][1]=bv; acc[j][2]=bv; acc[j][3]=bv;
                    }
                    #pragma unroll
                    for (int j = 0; j < 5; ++j) {
                        const int ct = half*5 + j;
                        const bf16x8 bb = *reinterpret_cast<const bf16x8*>(
                            &lds[LW1 + (ct*16 + lo)*40 + hi*8]);
                        acc[j] = __builtin_amdgcn_mfma_f32_16x16x32_bf16(a, bb, acc[j], 0,0,0);
                    }
                    #pragma unroll
                    for (int j = 0; j < 5; ++j)
                        #pragma unroll
                        for (int r = 0; r < 4; ++r)
                            act1m[(hi*4 + r)*168 + (half*5 + j)*16 + lo] =
                                f2bf(fmaxf(acc[j][r], 0.f));
                }
            }
            // ---- L2: act1 x W2F(global) -> act2 (private) ----
            {
                const ushort* w2p = WTR + W2F_OFF + (size_t)lane*8;
                asm volatile("" : "+v"(w2p));
                #pragma unroll
                for (int half = 0; half < 2; ++half) {
                    f32x4 acc[5];
                    #pragma unroll
                    for (int j = 0; j < 5; ++j) {
                        const int c = (half*5 + j)*16 + lo;
                        const float bv = (c < 150) ? bias[150 + c] : 0.f;
                        acc[j][0]=bv; acc[j][1]=bv; acc[j][2]=bv; acc[j][3]=bv;
                    }
                    #pragma unroll
                    for (int ks = 0; ks < 5; ++ks) {
                        const bf16x8 a = *reinterpret_cast<const bf16x8*>(
                            &act1m[lo*168 + ks*32 + hi*8]);
                        #pragma unroll
                        for (int j = 0; j < 5; ++j) {
                            const int ct = half*5 + j;
                            const bf16x8 bb = *reinterpret_cast<const bf16x8*>(
                                w2p + ((ct*5 + ks) << 9));
                            acc[j] = __builtin_amdgcn_mfma_f32_16x16x32_bf16(
                                a, bb, acc[j], 0,0,0);
                        }
                    }
                    #pragma unroll
                    for (int j = 0; j < 5; ++j)
                        #pragma unroll
                        for (int r = 0; r < 4; ++r)
                            act2m[(hi*4 + r)*168 + (half*5 + j)*16 + lo] =
                                f2bf(fmaxf(acc[j][r], 0.f));
                }
            }
            // ---- L3: act2 x W3F(global) -> ebuf[p] (E^T: [e][r]) ----
            {
                const ushort* w3p = WTR + W3F_OFF + (size_t)lane*8;
                asm volatile("" : "+v"(w3p));
                #pragma unroll
                for (int pass = 0; pass < 2; ++pass) {
                    const int nct = pass ? 3 : 4;
                    f32x4 acc[4];
                    #pragma unroll
                    for (int j = 0; j < 4; ++j) {
                        const int c = (pass*4 + j)*16 + lo;
                        const float bv = (j < nct && c < 100) ? bias[300 + c] : 0.f;
                        acc[j][0]=bv; acc[j][1]=bv; acc[j][2]=bv; acc[j][3]=bv;
                    }
                    #pragma unroll
                    for (int ks = 0; ks < 5; ++ks) {
                        const bf16x8 a = *reinterpret_cast<const bf16x8*>(
                            &act2m[lo*168 + ks*32 + hi*8]);
                        #pragma unroll
                        for (int j = 0; j < 4; ++j) {
                            if (j < nct) {
                                const int ct = pass*4 + j;
                                const bf16x8 bb = *reinterpret_cast<const bf16x8*>(
                                    w3p + ((ct*5 + ks) << 9));
                                acc[j] = __builtin_amdgcn_mfma_f32_16x16x32_bf16(
                                    a, bb, acc[j], 0,0,0);
                            }
                        }
                    }
                    #pragma unroll
                    for (int j = 0; j < 4; ++j) {
                        if (j < nct) {
                            const int e = (pass*4 + j)*16 + lo;
                            if (e < 100) {
                                uint2 u;
                                u.x = pk2(fmaxf(acc[j][0], 0.f), fmaxf(acc[j][1], 0.f));
                                u.y = pk2(fmaxf(acc[j][2], 0.f), fmaxf(acc[j][3], 0.f));
                                *reinterpret_cast<uint2*>(
                                    &eb[e*72 + m*16 + hi*4]) = u;
                            }
                        }
                    }
                }
            }
            __syncthreads();               // tile boundary (1 barrier/tile)
        }
    } else {
        // ================= S-waves: scatter + staging =================
        const int s = w - 4;
        f32x4 acc_er[2][7];
        #pragma unroll
        for (int part = 0; part < 2; ++part)
            #pragma unroll
            for (int ct = 0; ct < 7; ++ct)
                acc_er[part][ct] = (f32x4){0.f, 0.f, 0.f, 0.f};

        auto scat = [&](int pp) {
            ushort* bufR = lds + (pp ? LRR1 : LRR0);
            ushort* eb   = lds + (pp ? LEB1 : LEB0);
            #pragma unroll
            for (int part = 0; part < 2; ++part) {
                const int nt = s + part*4;
                if (nt < 7) {
                    #pragma unroll
                    for (int ks = 0; ks < 2; ++ks) {
                        const bf16x8 a = *reinterpret_cast<const bf16x8*>(
                            &bufR[(nt*16 + lo)*72 + ks*32 + hi*8]);
                        #pragma unroll
                        for (int ct = 0; ct < 7; ++ct) {
                            const bf16x8 bb = *reinterpret_cast<const bf16x8*>(
                                &eb[(ct*16 + lo)*72 + ks*32 + hi*8]);
                            acc_er[part][ct] = __builtin_amdgcn_mfma_f32_16x16x32_bf16(
                                a, bb, acc_er[part][ct], 0, 0, 0);
                        }
                    }
                }
            }
        };

        for (int k = tile0; k < tile1; ++k) {
            const int p = k & 1;
            if (k > tile0) scat(p ^ 1);        // scatter tile k-1
            if (k + 1 < tile1) stage(k + 1, (k + 1) & 1);
            __syncthreads();               // tile boundary (matches M-loop)
        }
        scat((tile1 - 1) & 1);             // last tile (after final barrier)

        // ---- ER partials: plain stores to this block's oct-slab ----
        float* ERq = ER + ((size_t)oct*B_ + b)*(size_t)(N_*EFF);
        #pragma unroll
        for (int part = 0; part < 2; ++part) {
            const int nt = s + part*4;
            if (nt < 7) {
                #pragma unroll
                for (int ct = 0; ct < 7; ++ct) {
                    const int e = ct*16 + lo;
                    if (e < EFF) {
                        #pragma unroll
                        for (int rg = 0; rg < 4; ++rg) {
                            const int n = nt*16 + hi*4 + rg;
                            if (n < N_)
                                ERq[n*EFF + e] = acc_er[part][ct][rg];
                        }
                    }
                }
            }
        }
    }
}

// ---------------------------------------------------------------------------
// Weight-image register staging (validated).
// ---------------------------------------------------------------------------
__device__ __forceinline__ void img_load(const ushort* __restrict__ g,
                                         uint4* pre, int t) {
    #pragma unroll
    for (int j = 0; j < 6; ++j) {
        int idx = t + j*256;
        int cidx = idx < 1440 ? idx : 1439;
        pre[j] = *reinterpret_cast<const uint4*>(g + (size_t)cidx*8);
    }
}
__device__ __forceinline__ void img_store(const uint4* pre, ushort* wt, int t) {
    #pragma unroll
    for (int j = 0; j < 6; ++j) {
        int idx = t + j*256;
        if (idx < 1440)
            *reinterpret_cast<uint4*>(wt + (size_t)idx*8) = pre[j];
    }
}

// ---------------------------------------------------------------------------
// MFMA dense layer for objmlp (validated round 6).
// ---------------------------------------------------------------------------
template<int COUT, int NCHUNK, int LASTKS, int NCT, bool RELU, int EPI, int ASTR>
__device__ __forceinline__ void mfma_layerO(
    const ushort* __restrict__ WT, const float* __restrict__ Bias,
    ushort* act, ushort* wt, int t, float* gout, int grow0)
{
    const int lane = t & 63;
    const int wv   = t >> 6;
    const int lo   = lane & 15;
    const int hi   = lane >> 4;

    f32x4 acc[2][NCT];
    #pragma unroll
    for (int ct = 0; ct < NCT; ++ct) {
        const int c = ct*16 + lo;
        const float bv = (c < COUT) ? Bias[c] : 0.f;
        #pragma unroll
        for (int m = 0; m < 2; ++m) {
            acc[m][ct][0] = bv; acc[m][ct][1] = bv;
            acc[m][ct][2] = bv; acc[m][ct][3] = bv;
        }
    }

    uint4 pre[6];
    img_load(WT, pre, t);
    #pragma unroll
    for (int q = 0; q < NCHUNK; ++q) {
        __syncthreads();
        img_store(pre, wt, t);
        if (q + 1 < NCHUNK) img_load(WT + (size_t)(q+1)*11520, pre, t);
        __syncthreads();
        const int nks = (q == NCHUNK-1) ? LASTKS : 2;
        #pragma unroll
        for (int ks = 0; ks < 2; ++ks) {
            if (ks < nks) {
                const int kg = q*64 + ks*32;
                const bf16x8 a0 = *reinterpret_cast<const bf16x8*>(
                    &act[(wv*32 +      lo)*ASTR + kg + hi*8]);
                const bf16x8 a1 = *reinterpret_cast<const bf16x8*>(
                    &act[(wv*32 + 16 + lo)*ASTR + kg + hi*8]);
                #pragma unroll
                for (int ct = 0; ct < NCT; ++ct) {
                    const bf16x8 b = *reinterpret_cast<const bf16x8*>(
                        &wt[(ct*16 + lo)*72 + ks*32 + hi*8]);
                    acc[0][ct] = __builtin_amdgcn_mfma_f32_16x16x32_bf16(
                        a0, b, acc[0][ct], 0, 0, 0);
                    acc[1][ct] = __builtin_amdgcn_mfma_f32_16x16x32_bf16(
                        a1, b, acc[1][ct], 0, 0, 0);
                }
            }
        }
    }

    __syncthreads();
    if (EPI == 0) {
        #pragma unroll
        for (int m = 0; m < 2; ++m)
            #pragma unroll
            for (int ct = 0; ct < NCT; ++ct)
                #pragma unroll
                for (int r = 0; r < 4; ++r) {
                    float v = acc[m][ct][r];
                    if (RELU) v = fmaxf(v, 0.f);
                    act[(wv*32 + m*16 + hi*4 + r)*ASTR + ct*16 + lo] = f2bf(v);
                }
    } else {
        #pragma unroll
        for (int m = 0; m < 2; ++m)
            #pragma unroll
            for (int r = 0; r < 4; ++r)
                if (lo < 2)
                    gout[(size_t)(grow0 + wv*32 + m*16 + hi*4 + r)*2 + lo] =
                        acc[m][0][r];
    }
    __syncthreads();
}

// ---------------------------------------------------------------------------
// K4: object MLP via MFMA (validated round 6). 50 blocks x 128 rows.
// ER is 8 per-oct slabs; sum them during the load.
// ---------------------------------------------------------------------------
#define OSTR 232
#define ERSL ((size_t)B_*N_*EFF)

__global__ __launch_bounds__(256, 1) void k_objmlp_mfma(
    const float* __restrict__ obj, const float* __restrict__ ER,
    const ushort* __restrict__ WO,
    const float* __restrict__ ob1, const float* __restrict__ ob2,
    const float* __restrict__ ob3, float* __restrict__ out)
{
    __shared__ __align__(16) ushort act[128*OSTR];
    __shared__ __align__(16) ushort wt[160*72];
    const int t = threadIdx.x;
    const int rowbase = blockIdx.x * 128;

    float4 per[13];
    #pragma unroll
    for (int j = 0; j < 13; ++j) {
        const int idx = t + j*256;
        const int ci = idx < 3200 ? idx : 3199;
        const int row = ci / 25, c = ci - row*25;
        const float* p = &ER[(size_t)(rowbase + row)*100 + c*4];
        float4 s = make_float4(0.f, 0.f, 0.f, 0.f);
        #pragma unroll
        for (int sl = 0; sl < 8; ++sl) {
            const float4 a = *reinterpret_cast<const float4*>(p + (size_t)sl*ERSL);
            s.x += a.x; s.y += a.y; s.z += a.z; s.w += a.w;
        }
        per[j] = s;
    }
    #pragma unroll
    for (int j = 0; j < 13; ++j) {
        const int idx = t + j*256;
        if (idx < 3200) {
            const int row = idx / 25, c = idx - row*25;
            ushort h[4], l[4];
            #pragma unroll
            for (int k = 0; k < 4; ++k) {
                const float f = ((const float*)&per[j])[k];
                h[k] = f2bf(f);
                l[k] = f2bf(f - bf2f(h[k]));
            }
            *reinterpret_cast<ushort4*>(&act[row*OSTR + 8 + c*4]) =
                make_ushort4(h[0], h[1], h[2], h[3]);
            *reinterpret_cast<ushort4*>(&act[row*OSTR + 108 + c*4]) =
                make_ushort4(l[0], l[1], l[2], l[3]);
        }
    }
    #pragma unroll
    for (int j = 0; j < 3; ++j) {
        const int idx = t + j*256;
        if (idx < 640) {
            const int row = idx / 5, d = idx - row*5;
            act[row*OSTR + d] = f2bf(obj[(size_t)(rowbase + row)*5 + d]);
        }
    }
    #pragma unroll
    for (int j = 0; j < 2; ++j) {
        const int idx = t + j*256;
        if (idx < 384) {
            const int row = idx / 3, c = 5 + (idx - row*3);
            act[row*OSTR + c] = 0;
        }
    }
    #pragma unroll
    for (int j = 0; j < 2; ++j) {
        const int idx = t + j*256;
        if (idx < 512) {
            const int row = idx >> 2, p = idx & 3;
            *reinterpret_cast<ushort4*>(&act[row*OSTR + 208 + p*4]) =
                make_ushort4(0, 0, 0, 0);
        }
    }

    mfma_layerO<100, 4, 1, 7, true,  0, OSTR>(WO,           ob1, act, wt, t, nullptr, 0);
    mfma_layerO<100, 2, 2, 7, true,  0, OSTR>(WO + 4*11520, ob2, act, wt, t, nullptr, 0);
    mfma_layerO<2,   2, 2, 1, false, 2, OSTR>(WO + 6*11520, ob3, act, wt, t, out, rowbase);
}

// ---------------------------------------------------------------------------
extern "C" void kernel_launch(void* const* d_in, const int* in_sizes, int n_in,
                              void* d_out, int out_size, void* d_ws, size_t ws_size,
                              hipStream_t stream)
{
    const float* objects = (const float*)d_in[0];
    const float* SR      = (const float*)d_in[1];
    const float* RR      = (const float*)d_in[2];
    const float* RI      = (const float*)d_in[3];
    const float* rW1 = (const float*)d_in[4];  const float* rb1 = (const float*)d_in[5];
    const float* rW2 = (const float*)d_in[6];  const float* rb2 = (const float*)d_in[7];
    const float* rW3 = (const float*)d_in[8];  const float* rb3 = (const float*)d_in[9];
    const float* oW1 = (const float*)d_in[10]; const float* ob1 = (const float*)d_in[11];
    const float* oW2 = (const float*)d_in[12]; const float* ob2 = (const float*)d_in[13];
    const float* oW3 = (const float*)d_in[14]; const float* ob3 = (const float*)d_in[15];
    float* out = (float*)d_out;

    // Workspace layout (~20.9 MB):
    //   ERp  fp32 [8 oct][B*N][100] = 20,480,000 B  @0   (fully written)
    //   WTR  bf16 187,776 ushorts   =    375,552 B  @20,480,000
    char* ws = (char*)d_ws;
    float*  ERp = (float*)ws;
    ushort* WTR = (ushort*)(ws + (size_t)8*B_*N_*EFF*sizeof(float));

    k_prepw<<<dim3(13), 256, 0, stream>>>(rW1, rW2, rW3, oW1, oW2, oW3, WTR);

    k_relmlp_p<<<dim3(512), 512, 0, stream>>>(objects, SR, RR, RI, WTR,
                                              rb1, rb2, rb3, ERp);

    k_objmlp_mfma<<<dim3(50), 256, 0, stream>>>(objects, ERp, WTR + WTR_OBJ,
                                                ob1, ob2, ob3, out);
}